// Round 7
// baseline (461.307 us; speedup 1.0000x reference)
//
#include <hip/hip_runtime.h>
#include <math.h>
#include <stdint.h>

// Problem: M=131072 rows, N=4000 verts, D=16. 250 real 16-col tiles, padded
// to 256 tiles (pad tiles carry ysq=65536 -> never win).
#define M_ROWS   131072
#define N_VERTS  4000
#define D_DIM    16
#define N_TILES_REAL 250
#define N_TILES  256
#define TILE_B   2048                 // B1 (64 lanes x 16B) + B2 (same)
#define CHUNK_T  16                   // tiles per LDS chunk
#define CHUNK_B  (CHUNK_T * TILE_B)   // 32768 B
#define N_CHUNKS (N_TILES / CHUNK_T)  // 16

// Scores biased +128 -> provably positive -> positive-float bits monotone as
// u32 -> min_u32 = fused best+argmin on keys = (score_bits & ~0xFF) | tile.
#define SCORE_BIAS 128.0f
// Error budget: key truncation <= 7.8e-3 (scores+bias < 512), arithmetic
// (dropped al*yl, ysq split, fp32 accum) <= ~1.5e-3. If the key-winner can
// differ from the true winner, measured gap <= 0.0186 < TIE_EPS -> rescanned.
#define TIE_EPS 0.025f

// d_ws layout (bytes):
//   [0      .. 524288)  yfrag : N_TILES x 2048 B (B1 | B2 fragments)
//   [524288 .. 524292)  cnt
//   [524352 .. ...   )  list  : ambiguous row indices
#define WS_CNT_OFF   (N_TILES * TILE_B)
#define WS_LIST_OFF  (WS_CNT_OFF + 64)

typedef float f32x4 __attribute__((ext_vector_type(4)));
typedef short s16x8 __attribute__((ext_vector_type(8)));

__device__ __forceinline__ unsigned short f32_to_bf16_rne(float f) {
    unsigned int u = __float_as_uint(f);
    u = (u + 0x7fffu + ((u >> 16) & 1u)) >> 16;
    return (unsigned short)u;
}
__device__ __forceinline__ float bf16_to_f32(unsigned short h) {
    return __uint_as_float(((unsigned int)h) << 16);
}
__device__ __forceinline__ uint32_t umin32(uint32_t a, uint32_t b) { return a < b ? a : b; }
__device__ __forceinline__ uint32_t umax32(uint32_t a, uint32_t b) { return a > b ? a : b; }

// ---------------------------------------------------------------------------
// Kernel 1: pack Y fragments (byte-identical scheme to R6, absmax=0 verified).
// Per (tile T, lane l): q=l>>4, c=l&15, n=T*16+c.
//   B1[j] = yh[(q&1)*8+j]
//   B2: q<2 -> yl[(q&1)*8+j]; q==2 -> (ysqb_hi, ysqb_lo, 0..); q==3 -> 0
// ysqb = ||y||^2 + SCORE_BIAS (pad tiles: y=0, ysqb=65536 -> never win).
// Pairs with screen's A1=[ah|al], A2=[ah|1,1,0..]: score+bias, no epilogue.
// ---------------------------------------------------------------------------
__global__ void pack_y_kernel(const float* __restrict__ verts,
                              char* __restrict__ yfrag,
                              int* __restrict__ cnt) {
    const int tid = blockIdx.x * blockDim.x + threadIdx.x;   // 0..16383
    if (tid == 0) *cnt = 0;
    const int T = tid >> 6;
    const int l = tid & 63;
    const int q = l >> 4;
    const int c = l & 15;

    float yv[16];
    float ysb;
    if (T < N_TILES_REAL) {
        const float* y = verts + (size_t)(T * 16 + c) * D_DIM;
#pragma unroll
        for (int d = 0; d < D_DIM; ++d) yv[d] = y[d];
        ysb = SCORE_BIAS;
#pragma unroll
        for (int d = 0; d < D_DIM; ++d) ysb = fmaf(yv[d], yv[d], ysb);
    } else {
#pragma unroll
        for (int d = 0; d < D_DIM; ++d) yv[d] = 0.f;
        ysb = 65536.f;    // dominates every real score; bf16-exact
    }

    const int half = (q & 1) * 8;
    const unsigned short ysq_hi = f32_to_bf16_rne(ysb);
    const unsigned short ysq_lo = f32_to_bf16_rne(ysb - bf16_to_f32(ysq_hi));
    s16x8 b1, b2;
#pragma unroll
    for (int j = 0; j < 8; ++j) {
        const float v = yv[half + j];
        const unsigned short hh = f32_to_bf16_rne(v);
        b1[j] = (short)hh;
        unsigned short b2v;
        if (q < 2)       b2v = f32_to_bf16_rne(v - bf16_to_f32(hh));  // yl
        else if (q == 2) b2v = (j == 0) ? ysq_hi : ((j == 1) ? ysq_lo : 0);
        else             b2v = 0;
        b2[j] = (short)b2v;
    }
    char* p = yfrag + (size_t)T * TILE_B + l * 16;
    *(s16x8*)p = b1;
    *(s16x8*)(p + 1024) = b2;
}

// ---------------------------------------------------------------------------
// Kernel 2 (MFMA screen): 256 thr = 4 waves; wave = 64 rows (4 row-groups of
// 16); block = 256 rows; grid = 512 (2 blocks/CU, LDS-capped). Per tile:
// 2 ds_read_b128 serve 8 MFMAs (16 scores/lane) -> LDS pipe ~20 us/CU <
// select VALU ~30 us. Staging: R5-proven 1-barrier reg-prefetch double
// buffer (16-tile chunks from the 512 KB yfrag in L2). Select: key =
// (bits&~0xFF)|tile; min_u32 = best+argmin, max+min = second.
// ---------------------------------------------------------------------------
__global__ __launch_bounds__(256, 2) void mfma_screen_kernel(
    const float* __restrict__ x_all,    // (M,16)
    const float* __restrict__ colors,   // (N,3)
    const char* __restrict__ yfrag,     // N_TILES x 2048 B
    float* __restrict__ out,            // (M,3)
    int* __restrict__ cnt,
    int* __restrict__ list,
    int list_cap)
{
    __shared__ __align__(16) char s_buf[2 * CHUNK_B];   // 64 KB (reused for reduce)

    const int tid  = threadIdx.x;
    const int wave = tid >> 6;
    const int lane = tid & 63;
    const int q = lane >> 4;
    const int c = lane & 15;
    const int rowBase = blockIdx.x * 256 + wave * 64;

    // --- A fragments for 4 row-groups. A1=[ah|al], A2=[ah|(1,1,0..)], a=-2x.
    s16x8 a1[4], a2[4];
#pragma unroll
    for (int g = 0; g < 4; ++g) {
        const float* xr = x_all + (size_t)(rowBase + g * 16 + c) * D_DIM + (q & 1) * 8;
        const float4 xa = *(const float4*)xr;
        const float4 xb = *(const float4*)(xr + 4);
        const float xv[8] = {xa.x, xa.y, xa.z, xa.w, xb.x, xb.y, xb.z, xb.w};
#pragma unroll
        for (int j = 0; j < 8; ++j) {
            const float a = -2.0f * xv[j];
            const unsigned short hh = f32_to_bf16_rne(a);
            const unsigned short ll = f32_to_bf16_rne(a - bf16_to_f32(hh));
            a1[g][j] = (short)((q < 2) ? hh : ll);
            unsigned short e = 0;
            if (q == 2 && j < 2) e = 0x3F80;   // bf16 1.0
            a2[g][j] = (short)((q < 2) ? hh : e);
        }
    }

    const f32x4 zero4 = {0.f, 0.f, 0.f, 0.f};
    uint32_t best[4][4], second[4][4];
#pragma unroll
    for (int g = 0; g < 4; ++g)
#pragma unroll
        for (int r = 0; r < 4; ++r) { best[g][r] = 0xFFFFFFFFu; second[g][r] = 0xFFFFFFFFu; }

    // --- Prologue: chunk 0 -> buf0 (identity copy; 8 int4 per thread).
    const int4* gy = (const int4*)yfrag;
    int4 pf[8];
#pragma unroll
    for (int i = 0; i < 8; ++i) pf[i] = gy[tid + i * 256];
    {
        int4* s = (int4*)s_buf;
#pragma unroll
        for (int i = 0; i < 8; ++i) s[tid + i * 256] = pf[i];
    }

    for (int ch = 0; ch < N_CHUNKS; ++ch) {
        // Prefetch next chunk into regs (latency overlapped with compute).
        if (ch + 1 < N_CHUNKS) {
            const int4* g = gy + (ch + 1) * (CHUNK_B / 16);
#pragma unroll
            for (int i = 0; i < 8; ++i) pf[i] = g[tid + i * 256];
        }
        __syncthreads();   // buf[ch&1] writes (prev tail / prologue) visible

        const char* bufc = s_buf + (ch & 1) * CHUNK_B + lane * 16;
#pragma unroll
        for (int t = 0; t < CHUNK_T; ++t) {
            const s16x8 b1 = *(const s16x8*)(bufc + t * TILE_B);
            const s16x8 b2 = *(const s16x8*)(bufc + t * TILE_B + 1024);
            const uint32_t tcur = (uint32_t)(ch * CHUNK_T + t);
#pragma unroll
            for (int g = 0; g < 4; ++g) {
                f32x4 acc = __builtin_amdgcn_mfma_f32_16x16x32_bf16(a1[g], b1, zero4, 0, 0, 0);
                acc = __builtin_amdgcn_mfma_f32_16x16x32_bf16(a2[g], b2, acc, 0, 0, 0);
#pragma unroll
                for (int r = 0; r < 4; ++r) {
                    const uint32_t kb = (__float_as_uint(acc[r]) & 0xFFFFFF00u) | tcur;
                    const uint32_t ob = best[g][r];
                    second[g][r] = umin32(second[g][r], umax32(ob, kb));
                    best[g][r]   = umin32(ob, kb);
                }
            }
        }
        // Write prefetched chunk to the other buffer (its last readers were
        // fenced by this iteration's top barrier).
        if (ch + 1 < N_CHUNKS) {
            int4* s = (int4*)(s_buf + ((ch + 1) & 1) * CHUNK_B);
#pragma unroll
            for (int i = 0; i < 8; ++i) s[tid + i * 256] = pf[i];
        }
    }

    // --- Cross-c reduce via LDS (stride 17 kills bank conflicts).
    __syncthreads();
    uint32_t* red  = (uint32_t*)s_buf;            // [4][64][17]
    uint32_t* red2 = red + 4 * 64 * 17;           // total 34816 B <= 64 KB
#pragma unroll
    for (int g = 0; g < 4; ++g)
#pragma unroll
        for (int r = 0; r < 4; ++r) {
            const int row = g * 16 + q * 4 + r;   // C/D: row = (lane>>4)*4 + reg
            red [wave * 1088 + row * 17 + c] = best[g][r];
            red2[wave * 1088 + row * 17 + c] = second[g][r];
        }
    __syncthreads();

    // Every thread finalizes one output row: row = lane of its wave.
    {
        uint32_t b1 = 0xFFFFFFFFu, b2 = 0xFFFFFFFFu, smin = 0xFFFFFFFFu;
        int cwin = 0;
#pragma unroll
        for (int cc = 0; cc < 16; ++cc) {
            const uint32_t k  = red [wave * 1088 + lane * 17 + cc];
            const uint32_t s2 = red2[wave * 1088 + lane * 17 + cc];
            smin = umin32(smin, s2);
            cwin = (k < b1) ? cc : cwin;      // strict <: earliest c on ties
            b2 = umin32(b2, umax32(b1, k));   // 2nd-min of bests
            b1 = umin32(b1, k);
        }
        const uint32_t secondAll = umin32(smin, b2);
        const float s1 = __uint_as_float(b1 & 0xFFFFFF00u);
        const float s2 = __uint_as_float(secondAll & 0xFFFFFF00u);
        const int n = (int)(b1 & 0xFFu) * 16 + cwin;
        const int m = rowBase + lane;

        bool amb = (s2 - s1 <= TIE_EPS);
        if (amb) {
            const int pos = atomicAdd(cnt, 1);
            if (pos < list_cap) list[pos] = m;
            else amb = false;                 // overflow: keep screened winner
        }
        if (!amb) {
            const float* cc2 = colors + (size_t)n * 3;
            float* o = out + (size_t)m * 3;
            o[0] = cc2[0];
            o[1] = cc2[1];
            o[2] = cc2[2];
        }
    }
}

// ---------------------------------------------------------------------------
// Kernel 3 (rescan): one wave per ambiguous row, fp64 exact. COALESCED:
// 4 lanes per vert (float4 each) -> one wave-step reads 16 verts = 1 KB
// contiguous (16 cache lines, vs 64-way scatter before). Linearized partial
// p = sum y*(y - 2x) -> 2 shuffle-adds per step. Lexicographic (p, v)
// butterfly = np.argmin first-index semantics (quad duplicates share (p,v)).
// ---------------------------------------------------------------------------
__global__ __launch_bounds__(256) void rescan_kernel(
    const float* __restrict__ x_all,
    const float* __restrict__ colors,
    const float* __restrict__ verts,
    const int* __restrict__ cnt,
    const int* __restrict__ list,
    int list_cap,
    float* __restrict__ out)
{
    const int wid  = blockIdx.x * 4 + (threadIdx.x >> 6);
    const int lane = threadIdx.x & 63;
    const int nWaves = gridDim.x * 4;
    const int v0 = lane >> 2;        // 0..15: vert within step
    const int qt = lane & 3;         // 0..3: float4 quarter of the vert row

    int ccount = *cnt;
    if (ccount > list_cap) ccount = list_cap;

    for (int rr = wid; rr < ccount; rr += nWaves) {
        const int m = list[rr];
        const float4 xf = *(const float4*)(x_all + (size_t)m * D_DIM + qt * 4);
        const double m2bx[4] = {-2.0 * (double)xf.x, -2.0 * (double)xf.y,
                                -2.0 * (double)xf.z, -2.0 * (double)xf.w};

        double best = INFINITY;
        int bi = 0x7fffffff;
#pragma unroll 2
        for (int step = 0; step < N_VERTS / 16; ++step) {
            const int v = step * 16 + v0;
            const float4 yf = *(const float4*)(verts + (size_t)v * D_DIM + qt * 4);
            const double y0 = (double)yf.x, y1 = (double)yf.y;
            const double y2 = (double)yf.z, y3 = (double)yf.w;
            double p = 0.0;
            p = fma(y0, y0 + m2bx[0], p);
            p = fma(y1, y1 + m2bx[1], p);
            p = fma(y2, y2 + m2bx[2], p);
            p = fma(y3, y3 + m2bx[3], p);
            // quad reduce: lanes 4k..4k+3 all end with the full score of v
            p += __shfl_xor(p, 1, 64);
            p += __shfl_xor(p, 2, 64);
            if (p < best || (p == best && v < bi)) { best = p; bi = v; }
        }
        // 64-lane lexicographic butterfly (quad duplicates are harmless).
#pragma unroll
        for (int off = 32; off > 0; off >>= 1) {
            const double ob = __shfl_xor(best, off, 64);
            const int    oi = __shfl_xor(bi, off, 64);
            if (ob < best || (ob == best && oi < bi)) { best = ob; bi = oi; }
        }
        if (lane == 0) {
            const float* cc = colors + (size_t)bi * 3;
            float* o = out + (size_t)m * 3;
            o[0] = cc[0];
            o[1] = cc[1];
            o[2] = cc[2];
        }
    }
}

// ---------------------------------------------------------------------------
extern "C" void kernel_launch(void* const* d_in, const int* in_sizes, int n_in,
                              void* d_out, int out_size, void* d_ws, size_t ws_size,
                              hipStream_t stream) {
    const float* cse_embedding       = (const float*)d_in[0]; // (M,16)
    const float* verts_colors        = (const float*)d_in[1]; // (N,3)
    const float* verts_cse_embedding = (const float*)d_in[2]; // (N,16)
    float* out = (float*)d_out;                               // (M,3)

    char* ws = (char*)d_ws;
    char* yfrag = ws;
    int*  cnt   = (int*)(ws + WS_CNT_OFF);
    int*  list  = (int*)(ws + WS_LIST_OFF);
    int list_cap = (int)((ws_size > WS_LIST_OFF)
                         ? ((ws_size - WS_LIST_OFF) / sizeof(int)) : 0);
    if (list_cap > M_ROWS) list_cap = M_ROWS;

    pack_y_kernel<<<(N_TILES * 64) / 256, 256, 0, stream>>>(
        verts_cse_embedding, yfrag, cnt);

    mfma_screen_kernel<<<M_ROWS / 256, 256, 0, stream>>>(
        cse_embedding, verts_colors, yfrag, out, cnt, list, list_cap);

    rescan_kernel<<<1024, 256, 0, stream>>>(
        cse_embedding, verts_colors, verts_cse_embedding, cnt, list,
        list_cap, out);
}

// Round 8
// 313.520 us; speedup vs baseline: 1.4714x; 1.4714x over previous
//
#include <hip/hip_runtime.h>
#include <math.h>
#include <stdint.h>

// Problem: M=131072 rows, N=4000 verts, D=16. 250 real 16-col tiles, padded
// to 256 tiles (pad tiles carry ysq=65536 -> never win).
#define M_ROWS   131072
#define N_VERTS  4000
#define D_DIM    16
#define N_TILES_REAL 250
#define N_TILES  256
#define TILE_B   2048                 // B1 (64 lanes x 16B) + B2 (same)
#define CHUNK_T  8                    // tiles per LDS chunk
#define CHUNK_B  (CHUNK_T * TILE_B)   // 16384 B
#define N_CHUNKS (N_TILES / CHUNK_T)  // 32

// Scores biased +128 -> provably positive -> positive-float bits monotone as
// u32 -> min_u32 = fused best+argmin on keys = (score_bits & ~0xFF) | tile.
#define SCORE_BIAS 128.0f
// Error budget: key truncation <= 7.8e-3 (scores+bias < 512), arithmetic
// (dropped al*yl, ysq split, fp32 accum) <= ~1.5e-3 -> bound ~1.1e-2.
// TIE_EPS = 0.02 > bound with ~2x margin; ~1.2% of rows rescan exactly.
#define TIE_EPS 0.02f

// d_ws layout (bytes):
//   [0      .. 524288)  yfrag : N_TILES x 2048 B (B1 | B2 fragments)
//   [524288 .. 524292)  cnt
//   [524352 .. ...   )  list  : ambiguous row indices
#define WS_CNT_OFF   (N_TILES * TILE_B)
#define WS_LIST_OFF  (WS_CNT_OFF + 64)

typedef float f32x4 __attribute__((ext_vector_type(4)));
typedef short s16x8 __attribute__((ext_vector_type(8)));

__device__ __forceinline__ unsigned short f32_to_bf16_rne(float f) {
    unsigned int u = __float_as_uint(f);
    u = (u + 0x7fffu + ((u >> 16) & 1u)) >> 16;
    return (unsigned short)u;
}
__device__ __forceinline__ float bf16_to_f32(unsigned short h) {
    return __uint_as_float(((unsigned int)h) << 16);
}
__device__ __forceinline__ uint32_t umin32(uint32_t a, uint32_t b) { return a < b ? a : b; }
__device__ __forceinline__ uint32_t umax32(uint32_t a, uint32_t b) { return a > b ? a : b; }

// ---------------------------------------------------------------------------
// Kernel 1: pack Y fragments (byte-identical scheme to R6/R7, absmax=0
// verified). Per (tile T, lane l): q=l>>4, c=l&15, n=T*16+c.
//   B1[j] = yh[(q&1)*8+j]
//   B2: q<2 -> yl[(q&1)*8+j]; q==2 -> (ysqb_hi, ysqb_lo, 0..); q==3 -> 0
// ysqb = ||y||^2 + SCORE_BIAS (pad tiles: y=0, ysqb=65536 -> never win).
// Pairs with screen's A1=[ah|al], A2=[ah|1,1,0..]: score+bias, no epilogue.
// ---------------------------------------------------------------------------
__global__ void pack_y_kernel(const float* __restrict__ verts,
                              char* __restrict__ yfrag,
                              int* __restrict__ cnt) {
    const int tid = blockIdx.x * blockDim.x + threadIdx.x;   // 0..16383
    if (tid == 0) *cnt = 0;
    const int T = tid >> 6;
    const int l = tid & 63;
    const int q = l >> 4;
    const int c = l & 15;

    float yv[16];
    float ysb;
    if (T < N_TILES_REAL) {
        const float* y = verts + (size_t)(T * 16 + c) * D_DIM;
#pragma unroll
        for (int d = 0; d < D_DIM; ++d) yv[d] = y[d];
        ysb = SCORE_BIAS;
#pragma unroll
        for (int d = 0; d < D_DIM; ++d) ysb = fmaf(yv[d], yv[d], ysb);
    } else {
#pragma unroll
        for (int d = 0; d < D_DIM; ++d) yv[d] = 0.f;
        ysb = 65536.f;    // dominates every real score; bf16-exact
    }

    const int half = (q & 1) * 8;
    const unsigned short ysq_hi = f32_to_bf16_rne(ysb);
    const unsigned short ysq_lo = f32_to_bf16_rne(ysb - bf16_to_f32(ysq_hi));
    s16x8 b1, b2;
#pragma unroll
    for (int j = 0; j < 8; ++j) {
        const float v = yv[half + j];
        const unsigned short hh = f32_to_bf16_rne(v);
        b1[j] = (short)hh;
        unsigned short b2v;
        if (q < 2)       b2v = f32_to_bf16_rne(v - bf16_to_f32(hh));  // yl
        else if (q == 2) b2v = (j == 0) ? ysq_hi : ((j == 1) ? ysq_lo : 0);
        else             b2v = 0;
        b2[j] = (short)b2v;
    }
    char* p = yfrag + (size_t)T * TILE_B + l * 16;
    *(s16x8*)p = b1;
    *(s16x8*)(p + 1024) = b2;
}

// ---------------------------------------------------------------------------
// Kernel 2 (MFMA screen): R5's proven shape — 512 thr = 8 waves, wave = 16
// rows (ONE row-group: VGPR ~40, no spill; R7's 4-group wave spilled 1.3 GB).
// ysq folded into B2/A2 -> zero per-tile acc-init, no ysq ds_read.
// 8-tile chunks (16 KB), dbuf = 32 KB LDS -> 4 blocks/CU = 32 waves/CU.
// Grid = 1024 blocks = exactly one full-occupancy round.
// Select: key=(bits&~0xFF)|tile; min_u32=best+argmin, max+min=second.
// ---------------------------------------------------------------------------
__global__ __launch_bounds__(512, 6) void mfma_screen_kernel(
    const float* __restrict__ x_all,    // (M,16)
    const float* __restrict__ colors,   // (N,3)
    const char* __restrict__ yfrag,     // N_TILES x 2048 B
    float* __restrict__ out,            // (M,3)
    int* __restrict__ cnt,
    int* __restrict__ list,
    int list_cap)
{
    __shared__ __align__(16) char s_buf[2 * CHUNK_B];   // 32 KB (reused for reduce)

    const int tid  = threadIdx.x;
    const int wave = tid >> 6;
    const int lane = tid & 63;
    const int q = lane >> 4;
    const int c = lane & 15;
    const int rowBase = blockIdx.x * 128 + wave * 16;

    // --- A fragments. A1 = [ah | al], A2 = [ah | (1,1,0,..)] of a = -2x.
    const float* xr = x_all + (size_t)(rowBase + c) * D_DIM + (q & 1) * 8;
    const float4 xa = *(const float4*)xr;
    const float4 xb = *(const float4*)(xr + 4);
    const float xv[8] = {xa.x, xa.y, xa.z, xa.w, xb.x, xb.y, xb.z, xb.w};
    s16x8 a1, a2;
#pragma unroll
    for (int j = 0; j < 8; ++j) {
        const float a = -2.0f * xv[j];
        const unsigned short hh = f32_to_bf16_rne(a);
        const unsigned short ll = f32_to_bf16_rne(a - bf16_to_f32(hh));
        a1[j] = (short)((q < 2) ? hh : ll);
        unsigned short e = 0;
        if (q == 2 && j < 2) e = 0x3F80;   // bf16 1.0
        a2[j] = (short)((q < 2) ? hh : e);
    }

    const f32x4 zero4 = {0.f, 0.f, 0.f, 0.f};
    uint32_t best[4]   = {0xFFFFFFFFu, 0xFFFFFFFFu, 0xFFFFFFFFu, 0xFFFFFFFFu};
    uint32_t second[4] = {0xFFFFFFFFu, 0xFFFFFFFFu, 0xFFFFFFFFu, 0xFFFFFFFFu};

    // --- Prologue: chunk 0 -> buf0 (16 KB = 1024 int4; 2 per thread).
    const int4* gy = (const int4*)yfrag;
    int4 p0 = gy[tid];
    int4 p1 = gy[tid + 512];
    {
        int4* s = (int4*)s_buf;
        s[tid] = p0;
        s[tid + 512] = p1;
    }

    for (int ch = 0; ch < N_CHUNKS; ++ch) {
        // Prefetch next chunk into regs (latency overlapped with compute).
        if (ch + 1 < N_CHUNKS) {
            const int4* g = gy + (ch + 1) * (CHUNK_B / 16);
            p0 = g[tid];
            p1 = g[tid + 512];
        }
        __syncthreads();   // buf[ch&1] writes (prev tail / prologue) visible

        const char* bufc = s_buf + (ch & 1) * CHUNK_B + lane * 16;
#pragma unroll
        for (int t = 0; t < CHUNK_T; ++t) {
            const s16x8 b1 = *(const s16x8*)(bufc + t * TILE_B);
            const s16x8 b2 = *(const s16x8*)(bufc + t * TILE_B + 1024);
            f32x4 acc = __builtin_amdgcn_mfma_f32_16x16x32_bf16(a1, b1, zero4, 0, 0, 0);
            acc = __builtin_amdgcn_mfma_f32_16x16x32_bf16(a2, b2, acc, 0, 0, 0);
            const uint32_t tcur = (uint32_t)(ch * CHUNK_T + t);
#pragma unroll
            for (int r = 0; r < 4; ++r) {
                const uint32_t kb = (__float_as_uint(acc[r]) & 0xFFFFFF00u) | tcur;
                const uint32_t ob = best[r];
                second[r] = umin32(second[r], umax32(ob, kb));
                best[r]   = umin32(ob, kb);
            }
        }
        // Write prefetched chunk to the other buffer (its last readers were
        // fenced by this iteration's top barrier).
        if (ch + 1 < N_CHUNKS) {
            int4* s = (int4*)(s_buf + ((ch + 1) & 1) * CHUNK_B);
            s[tid] = p0;
            s[tid + 512] = p1;
        }
    }

    // --- Cross-c reduce via LDS (R5-proven epilogue). 8 KB + 8 KB in s_buf.
    __syncthreads();
    uint32_t* s_red  = (uint32_t*)s_buf;
    uint32_t* s_red2 = (uint32_t*)(s_buf + 8192);
#pragma unroll
    for (int r = 0; r < 4; ++r) {
        const int row = q * 4 + r;            // C/D: row = (lane>>4)*4 + reg
        s_red [wave * 256 + row * 16 + c] = best[r];
        s_red2[wave * 256 + row * 16 + c] = second[r];
    }
    __syncthreads();

    if (lane < 16) {
        const int row = lane;
        uint32_t b1 = 0xFFFFFFFFu, b2 = 0xFFFFFFFFu, smin = 0xFFFFFFFFu;
        int cwin = 0;
#pragma unroll
        for (int cc = 0; cc < 16; ++cc) {
            const uint32_t k  = s_red [wave * 256 + row * 16 + cc];
            const uint32_t s2 = s_red2[wave * 256 + row * 16 + cc];
            smin = umin32(smin, s2);
            cwin = (k < b1) ? cc : cwin;      // strict <: earliest c on ties
            b2 = umin32(b2, umax32(b1, k));   // 2nd-min of bests
            b1 = umin32(b1, k);
        }
        const uint32_t secondAll = umin32(smin, b2);
        const float s1 = __uint_as_float(b1 & 0xFFFFFF00u);
        const float s2 = __uint_as_float(secondAll & 0xFFFFFF00u);
        const int n = (int)(b1 & 0xFFu) * 16 + cwin;
        const int m = rowBase + row;

        bool amb = (s2 - s1 <= TIE_EPS);
        if (amb) {
            const int pos = atomicAdd(cnt, 1);
            if (pos < list_cap) list[pos] = m;
            else amb = false;                 // overflow: keep screened winner
        }
        if (!amb) {
            const float* cc2 = colors + (size_t)n * 3;
            float* o = out + (size_t)m * 3;
            o[0] = cc2[0];
            o[1] = cc2[1];
            o[2] = cc2[2];
        }
    }
}

// ---------------------------------------------------------------------------
// Kernel 3 (rescan): one wave per ambiguous row, fp64 exact, COALESCED:
// 4 lanes per vert (float4 each) -> wave-step reads 16 verts = 1 KB
// contiguous. Linearized p = sum y*(y-2x); quad shuffle-add; lexicographic
// (p, v) butterfly = np.argmin first-index semantics.
// ---------------------------------------------------------------------------
__global__ __launch_bounds__(256) void rescan_kernel(
    const float* __restrict__ x_all,
    const float* __restrict__ colors,
    const float* __restrict__ verts,
    const int* __restrict__ cnt,
    const int* __restrict__ list,
    int list_cap,
    float* __restrict__ out)
{
    const int wid  = blockIdx.x * 4 + (threadIdx.x >> 6);
    const int lane = threadIdx.x & 63;
    const int nWaves = gridDim.x * 4;
    const int v0 = lane >> 2;        // 0..15: vert within step
    const int qt = lane & 3;         // 0..3: float4 quarter of the vert row

    int ccount = *cnt;
    if (ccount > list_cap) ccount = list_cap;

    for (int rr = wid; rr < ccount; rr += nWaves) {
        const int m = list[rr];
        const float4 xf = *(const float4*)(x_all + (size_t)m * D_DIM + qt * 4);
        const double m2bx[4] = {-2.0 * (double)xf.x, -2.0 * (double)xf.y,
                                -2.0 * (double)xf.z, -2.0 * (double)xf.w};

        double best = INFINITY;
        int bi = 0x7fffffff;
#pragma unroll 2
        for (int step = 0; step < N_VERTS / 16; ++step) {
            const int v = step * 16 + v0;
            const float4 yf = *(const float4*)(verts + (size_t)v * D_DIM + qt * 4);
            const double y0 = (double)yf.x, y1 = (double)yf.y;
            const double y2 = (double)yf.z, y3 = (double)yf.w;
            double p = 0.0;
            p = fma(y0, y0 + m2bx[0], p);
            p = fma(y1, y1 + m2bx[1], p);
            p = fma(y2, y2 + m2bx[2], p);
            p = fma(y3, y3 + m2bx[3], p);
            // quad reduce: lanes 4k..4k+3 all end with the full score of v
            p += __shfl_xor(p, 1, 64);
            p += __shfl_xor(p, 2, 64);
            if (p < best || (p == best && v < bi)) { best = p; bi = v; }
        }
        // 64-lane lexicographic butterfly (quad duplicates are harmless).
#pragma unroll
        for (int off = 32; off > 0; off >>= 1) {
            const double ob = __shfl_xor(best, off, 64);
            const int    oi = __shfl_xor(bi, off, 64);
            if (ob < best || (ob == best && oi < bi)) { best = ob; bi = oi; }
        }
        if (lane == 0) {
            const float* cc = colors + (size_t)bi * 3;
            float* o = out + (size_t)m * 3;
            o[0] = cc[0];
            o[1] = cc[1];
            o[2] = cc[2];
        }
    }
}

// ---------------------------------------------------------------------------
extern "C" void kernel_launch(void* const* d_in, const int* in_sizes, int n_in,
                              void* d_out, int out_size, void* d_ws, size_t ws_size,
                              hipStream_t stream) {
    const float* cse_embedding       = (const float*)d_in[0]; // (M,16)
    const float* verts_colors        = (const float*)d_in[1]; // (N,3)
    const float* verts_cse_embedding = (const float*)d_in[2]; // (N,16)
    float* out = (float*)d_out;                               // (M,3)

    char* ws = (char*)d_ws;
    char* yfrag = ws;
    int*  cnt   = (int*)(ws + WS_CNT_OFF);
    int*  list  = (int*)(ws + WS_LIST_OFF);
    int list_cap = (int)((ws_size > WS_LIST_OFF)
                         ? ((ws_size - WS_LIST_OFF) / sizeof(int)) : 0);
    if (list_cap > M_ROWS) list_cap = M_ROWS;

    pack_y_kernel<<<(N_TILES * 64) / 256, 256, 0, stream>>>(
        verts_cse_embedding, yfrag, cnt);

    mfma_screen_kernel<<<M_ROWS / 128, 512, 0, stream>>>(
        cse_embedding, verts_colors, yfrag, out, cnt, list, list_cap);

    rescan_kernel<<<512, 256, 0, stream>>>(
        cse_embedding, verts_colors, verts_cse_embedding, cnt, list,
        list_cap, out);
}